// Round 1
// baseline (582.162 us; speedup 1.0000x reference)
//
#include <hip/hip_runtime.h>
#include <hip/hip_bf16.h>

// FastASTEncoder: B=16, N=512, DM=512, H=8 (4 par + 4 bro), DK=64, R=8, L=2, DFF=2048
// Strategy: bf16 MFMA GEMMs (16x16x32), fp32 everywhere else.
// Workspace layout (needs ~108 MiB):
//   [0,16M)    q        fp32 [8192][512]   (reused as t1 gemm-out after attention)
//   [16M,32M)  k        fp32
//   [32M,48M)  v        fp32
//   [48M,80M)  h1       bf16 [8192][2048]
//   [80M,88M)  xb       bf16 [8192][512]   (bf16 copy of activations)
//   [88M,96M)  cb       bf16 [8192][512]   (attention context, bf16)
//   [96M,108M) transposed bf16 weights

#define BB 16
#define NN 512
#define DMM 512
#define HH 8
#define DKK 64
#define RR 8
#define LL 2
#define DFF 2048
#define PAR_HEADS 4
#define EPSV 1e-5f

typedef __bf16 bf16x8 __attribute__((ext_vector_type(8)));
typedef float f32x4 __attribute__((ext_vector_type(4)));

__device__ __forceinline__ unsigned short f2bf(float f) {
    unsigned u = __float_as_uint(f);
    u += 0x7fff + ((u >> 16) & 1);   // RNE
    return (unsigned short)(u >> 16);
}

// ---------------- weight transpose: [z][K][N] fp32 -> [z][N][K] bf16 ----------------
__global__ __launch_bounds__(256) void transpose_w_kernel(
    const float* __restrict__ src, unsigned short* __restrict__ dst, int K, int N)
{
    __shared__ float tile[32][33];
    size_t zoff = (size_t)blockIdx.z * K * N;
    const float* s = src + zoff;
    unsigned short* d = dst + zoff;
    int k0 = blockIdx.y * 32, n0 = blockIdx.x * 32;
    int tx = threadIdx.x & 31, ty = threadIdx.x >> 5;   // 32 x 8
#pragma unroll
    for (int i = 0; i < 4; ++i)
        tile[ty + i * 8][tx] = s[(size_t)(k0 + ty + i * 8) * N + (n0 + tx)];
    __syncthreads();
#pragma unroll
    for (int i = 0; i < 4; ++i)
        d[(size_t)(n0 + ty + i * 8) * K + (k0 + tx)] = f2bf(tile[tx][ty + i * 8]);
}

// ---------------- x init: copy src_emb -> x (fp32) and xb (bf16) ----------------
__global__ __launch_bounds__(256) void convert_x_kernel(
    const float* __restrict__ src, float* __restrict__ x, unsigned short* __restrict__ xb, int n4)
{
    int i = blockIdx.x * blockDim.x + threadIdx.x;
    int stride = gridDim.x * blockDim.x;
    for (; i < n4; i += stride) {
        float4 f = ((const float4*)src)[i];
        ((float4*)x)[i] = f;
        ushort4 u;
        u.x = f2bf(f.x); u.y = f2bf(f.y); u.z = f2bf(f.z); u.w = f2bf(f.w);
        ((ushort4*)xb)[i] = u;
    }
}

// ---------------- bf16 GEMM: C[M][N] = A[M][K] @ Bt[N][K]^T (+bias, relu, bf16/f32 out) ----
#define BM 128
#define BN 128
#define BK 32

__global__ __launch_bounds__(256) void gemm_bt_kernel(
    const unsigned short* __restrict__ A,   // [M][K] bf16
    const unsigned short* __restrict__ Bt,  // [N][K] bf16 (i.e. W^T)
    float* __restrict__ Cf,                 // [M][N] fp32 out (if Cb null)
    unsigned short* __restrict__ Cb,        // [M][N] bf16 out (optional)
    const float* __restrict__ bias,         // [N] or null
    int M, int N, int K, int relu)
{
    __shared__ __align__(16) unsigned short As[BM * BK];
    __shared__ __align__(16) unsigned short Bs[BN * BK];
    int tid = threadIdx.x;
    int lane = tid & 63;
    int w = tid >> 6;
    int wr = w >> 1, wc = w & 1;
    int mBase = blockIdx.y * BM;
    int nBase = blockIdx.x * BN;

    f32x4 acc[4][4];
#pragma unroll
    for (int i = 0; i < 4; ++i)
#pragma unroll
        for (int j = 0; j < 4; ++j) acc[i][j] = (f32x4){0.f, 0.f, 0.f, 0.f};

    int ldRow = lane >> 2;         // 0..15 within chunk
    int ldCol = (lane & 3) * 8;    // 0,8,16,24

    for (int k0 = 0; k0 < K; k0 += BK) {
        // stage A,B tiles: 8 chunks of 16 rows x 32 cols each; wave w does chunks w and 4+w
#pragma unroll
        for (int it = 0; it < 2; ++it) {
            int c = it * 4 + w;
            int row = c * 16 + ldRow;
            const unsigned short* ga = A + (size_t)(mBase + row) * K + k0 + ldCol;
            __builtin_amdgcn_global_load_lds(
                (const __attribute__((address_space(1))) void*)ga,
                (__attribute__((address_space(3))) void*)(As + c * 512), 16, 0, 0);
            const unsigned short* gb = Bt + (size_t)(nBase + row) * K + k0 + ldCol;
            __builtin_amdgcn_global_load_lds(
                (const __attribute__((address_space(1))) void*)gb,
                (__attribute__((address_space(3))) void*)(Bs + c * 512), 16, 0, 0);
        }
        __syncthreads();

        int kof = (lane >> 4) * 8;
        int rsel = lane & 15;
        bf16x8 a[4], b[4];
#pragma unroll
        for (int m = 0; m < 4; ++m)
            a[m] = *(const bf16x8*)(As + (wr * 64 + m * 16 + rsel) * BK + kof);
#pragma unroll
        for (int n = 0; n < 4; ++n)
            b[n] = *(const bf16x8*)(Bs + (wc * 64 + n * 16 + rsel) * BK + kof);
#pragma unroll
        for (int m = 0; m < 4; ++m)
#pragma unroll
            for (int n = 0; n < 4; ++n)
                acc[m][n] = __builtin_amdgcn_mfma_f32_16x16x32_bf16(a[m], b[n], acc[m][n], 0, 0, 0);
        __syncthreads();
    }

    // epilogue: C/D layout col=lane&15, row=(lane>>4)*4+j  [m89-verified]
    int rbase = (lane >> 4) * 4;
    int cloc = lane & 15;
#pragma unroll
    for (int m = 0; m < 4; ++m) {
#pragma unroll
        for (int n = 0; n < 4; ++n) {
            int col = nBase + wc * 64 + n * 16 + cloc;
            float bv = bias ? bias[col] : 0.0f;
#pragma unroll
            for (int j = 0; j < 4; ++j) {
                int row = mBase + wr * 64 + m * 16 + rbase + j;
                float val = acc[m][n][j] + bv;
                if (relu) val = fmaxf(val, 0.0f);
                if (Cb) Cb[(size_t)row * N + col] = f2bf(val);
                else    Cf[(size_t)row * N + col] = val;
            }
        }
    }
}

// ---------------- sparse relational attention ----------------
// one wave per (b,h,n); lane = d (DK=64)
__global__ __launch_bounds__(256) void attn_kernel(
    const float* __restrict__ q, const float* __restrict__ k, const float* __restrict__ v,
    const int* __restrict__ par, const int* __restrict__ bro,
    const float* __restrict__ relq, const float* __restrict__ relk, const float* __restrict__ relv,
    unsigned short* __restrict__ cb)
{
    int wid = blockIdx.x * 4 + (threadIdx.x >> 6);
    int lane = threadIdx.x & 63;
    int n = wid & (NN - 1);
    int t = wid >> 9;           // / NN
    int h = t & (HH - 1);
    int b = t >> 3;
    const int* edges = (h < PAR_HEADS) ? par : bro;

    float qd = q[(size_t)(b * NN + n) * DMM + h * DKK + lane];
    float s[RR];
    int e[RR];
#pragma unroll
    for (int r = 0; r < RR; ++r) {
        e[r] = edges[(b * RR + r) * NN + n];
        float kd = k[(size_t)(b * NN + e[r]) * DMM + h * DKK + lane];
        float rkd = relk[(h * RR + r) * DKK + lane];
        float rqd = relq[(h * RR + r) * DKK + lane];
        float tp = qd * kd + qd * rkd + rqd * kd;
#pragma unroll
        for (int off = 32; off > 0; off >>= 1) tp += __shfl_xor(tp, off, 64);
        s[r] = tp;
    }
    const float scale = 0.125f;  // 1/sqrt(64)
    float mx = -1e30f;
#pragma unroll
    for (int r = 0; r < RR; ++r) { s[r] *= scale; mx = fmaxf(mx, s[r]); }
    float denom = 0.f;
#pragma unroll
    for (int r = 0; r < RR; ++r) { s[r] = __expf(s[r] - mx); denom += s[r]; }
    float inv = 1.0f / denom;
    float od = 0.f;
#pragma unroll
    for (int r = 0; r < RR; ++r) {
        float vd = v[(size_t)(b * NN + e[r]) * DMM + h * DKK + lane];
        float rvd = relv[(h * RR + r) * DKK + lane];
        od += s[r] * (vd + rvd);
    }
    od *= inv;
    cb[(size_t)(b * NN + n) * DMM + h * DKK + lane] = f2bf(od);
}

// ---------------- residual + LayerNorm (optionally add, optionally bf16 out) ----------------
// one wave per row of 512
__global__ __launch_bounds__(256) void ln_kernel(
    const float* __restrict__ xin, const float* __restrict__ add,
    float* __restrict__ xout, unsigned short* __restrict__ xbout,
    const float* __restrict__ g, const float* __restrict__ bb)
{
    int row = blockIdx.x * 4 + (threadIdx.x >> 6);
    int lane = threadIdx.x & 63;
    const float* xr = xin + (size_t)row * DMM;
    const float* ar = add ? add + (size_t)row * DMM : nullptr;
    float vals[8];
    float s = 0.f;
#pragma unroll
    for (int j = 0; j < 8; ++j) {
        int c = lane + j * 64;
        float t = xr[c] + (ar ? ar[c] : 0.f);
        vals[j] = t;
        s += t;
    }
#pragma unroll
    for (int off = 32; off > 0; off >>= 1) s += __shfl_xor(s, off, 64);
    float mean = s * (1.0f / DMM);
    float s2 = 0.f;
#pragma unroll
    for (int j = 0; j < 8; ++j) { float d = vals[j] - mean; s2 += d * d; }
#pragma unroll
    for (int off = 32; off > 0; off >>= 1) s2 += __shfl_xor(s2, off, 64);
    float inv = rsqrtf(s2 * (1.0f / DMM) + EPSV);
#pragma unroll
    for (int j = 0; j < 8; ++j) {
        int c = lane + j * 64;
        float y = (vals[j] - mean) * inv * g[c] + bb[c];
        xout[(size_t)row * DMM + c] = y;
        if (xbout) xbout[(size_t)row * DMM + c] = f2bf(y);
    }
}

extern "C" void kernel_launch(void* const* d_in, const int* in_sizes, int n_in,
                              void* d_out, int out_size, void* d_ws, size_t ws_size,
                              hipStream_t stream)
{
    const float* src_emb = (const float*)d_in[0];
    const int*   par     = (const int*)d_in[1];
    const int*   bro     = (const int*)d_in[2];
    const float* rel_q   = (const float*)d_in[3];
    const float* rel_k   = (const float*)d_in[4];
    const float* rel_v   = (const float*)d_in[5];
    const float* Wq      = (const float*)d_in[6];
    const float* Wk      = (const float*)d_in[7];
    const float* Wv      = (const float*)d_in[8];
    const float* Wo      = (const float*)d_in[9];
    const float* ln1_g   = (const float*)d_in[10];
    const float* ln1_b   = (const float*)d_in[11];
    const float* W1      = (const float*)d_in[12];
    const float* b1      = (const float*)d_in[13];
    const float* W2      = (const float*)d_in[14];
    const float* b2      = (const float*)d_in[15];
    const float* ln2_g   = (const float*)d_in[16];
    const float* ln2_b   = (const float*)d_in[17];
    const float* normf_g = (const float*)d_in[18];
    const float* normf_b = (const float*)d_in[19];

    const size_t MB = 1024 * 1024;
    const int M = BB * NN;  // 8192
    char* ws = (char*)d_ws;
    float* q  = (float*)(ws + 0 * MB);
    float* kk = (float*)(ws + 16 * MB);
    float* vv = (float*)(ws + 32 * MB);
    unsigned short* h1   = (unsigned short*)(ws + 48 * MB);
    unsigned short* xb   = (unsigned short*)(ws + 80 * MB);
    unsigned short* cbuf = (unsigned short*)(ws + 88 * MB);
    unsigned short* wqT  = (unsigned short*)(ws + 96 * MB);
    unsigned short* wkT  = wqT + (size_t)LL * DMM * DMM;
    unsigned short* wvT  = wkT + (size_t)LL * DMM * DMM;
    unsigned short* woT  = wvT + (size_t)LL * DMM * DMM;
    unsigned short* w1T  = woT + (size_t)LL * DMM * DMM;
    unsigned short* w2T  = w1T + (size_t)LL * DMM * DFF;
    float* t1 = q;           // reuse q after attention
    float* x  = (float*)d_out;

    // weight transposes (fp32 -> bf16 [N][K], per layer via blockIdx.z)
    transpose_w_kernel<<<dim3(DMM / 32, DMM / 32, LL), 256, 0, stream>>>(Wq, wqT, DMM, DMM);
    transpose_w_kernel<<<dim3(DMM / 32, DMM / 32, LL), 256, 0, stream>>>(Wk, wkT, DMM, DMM);
    transpose_w_kernel<<<dim3(DMM / 32, DMM / 32, LL), 256, 0, stream>>>(Wv, wvT, DMM, DMM);
    transpose_w_kernel<<<dim3(DMM / 32, DMM / 32, LL), 256, 0, stream>>>(Wo, woT, DMM, DMM);
    transpose_w_kernel<<<dim3(DFF / 32, DMM / 32, LL), 256, 0, stream>>>(W1, w1T, DMM, DFF);
    transpose_w_kernel<<<dim3(DMM / 32, DFF / 32, LL), 256, 0, stream>>>(W2, w2T, DFF, DMM);

    convert_x_kernel<<<2048, 256, 0, stream>>>(src_emb, x, xb, M * DMM / 4);

    for (int l = 0; l < LL; ++l) {
        const unsigned short* wq_l = wqT + (size_t)l * DMM * DMM;
        const unsigned short* wk_l = wkT + (size_t)l * DMM * DMM;
        const unsigned short* wv_l = wvT + (size_t)l * DMM * DMM;
        const unsigned short* wo_l = woT + (size_t)l * DMM * DMM;
        const unsigned short* w1_l = w1T + (size_t)l * DMM * DFF;
        const unsigned short* w2_l = w2T + (size_t)l * DFF * DMM;

        dim3 g512(DMM / BN, M / BM);   // (4, 64)
        gemm_bt_kernel<<<g512, 256, 0, stream>>>(xb, wq_l, q,  nullptr, nullptr, M, DMM, DMM, 0);
        gemm_bt_kernel<<<g512, 256, 0, stream>>>(xb, wk_l, kk, nullptr, nullptr, M, DMM, DMM, 0);
        gemm_bt_kernel<<<g512, 256, 0, stream>>>(xb, wv_l, vv, nullptr, nullptr, M, DMM, DMM, 0);

        attn_kernel<<<BB * HH * NN / 4, 256, 0, stream>>>(q, kk, vv, par, bro,
                                                          rel_q, rel_k, rel_v, cbuf);

        gemm_bt_kernel<<<g512, 256, 0, stream>>>(cbuf, wo_l, t1, nullptr, nullptr, M, DMM, DMM, 0);
        ln_kernel<<<M / 4, 256, 0, stream>>>(x, t1, x, xb, ln1_g + l * DMM, ln1_b + l * DMM);

        gemm_bt_kernel<<<dim3(DFF / BN, M / BM), 256, 0, stream>>>(
            xb, w1_l, nullptr, h1, b1 + l * DFF, M, DFF, DMM, 1);
        gemm_bt_kernel<<<g512, 256, 0, stream>>>(h1, w2_l, t1, nullptr, b2 + l * DMM, M, DMM, DFF, 0);
        ln_kernel<<<M / 4, 256, 0, stream>>>(x, t1, x, xb, ln2_g + l * DMM, ln2_b + l * DMM);
    }

    ln_kernel<<<M / 4, 256, 0, stream>>>(x, nullptr, x, nullptr, normf_g, normf_b);
}

// Round 2
// 461.511 us; speedup vs baseline: 1.2614x; 1.2614x over previous
//
#include <hip/hip_runtime.h>
#include <hip/hip_bf16.h>

// FastASTEncoder: B=16, N=512, DM=512, H=8 (4 par + 4 bro), DK=64, R=8, L=2, DFF=2048
// Round 2: fused QKV GEMM (N=1536), BN=64 tiles for N=512 GEMMs (2 blocks/CU),
// XCD-bijective block swizzle, LDS slot-XOR swizzle (both-sides), bf16 qkv for attention.
//
// Workspace layout (~100 MiB):
//   [0,24M)   qkvb  bf16 [8192][1536]
//   [24M,40M) t1    fp32 [8192][512]
//   [40M,72M) h1    bf16 [8192][2048]
//   [72M,80M) xb    bf16 [8192][512]
//   [80M,88M) cbuf  bf16 [8192][512]
//   [88M,...) transposed bf16 weights (qkv packed, wo, w1, w2)

#define BB 16
#define NN 512
#define DMM 512
#define HH 8
#define DKK 64
#define RR 8
#define LL 2
#define DFFV 2048
#define PAR_HEADS 4
#define EPSV 1e-5f

typedef __bf16 bf16x8 __attribute__((ext_vector_type(8)));
typedef float f32x4 __attribute__((ext_vector_type(4)));

__device__ __forceinline__ unsigned short f2bf(float f) {
    unsigned u = __float_as_uint(f);
    u += 0x7fff + ((u >> 16) & 1);   // RNE
    return (unsigned short)(u >> 16);
}
__device__ __forceinline__ float bf2f(unsigned short u) {
    return __uint_as_float(((unsigned)u) << 16);
}

// ---------------- weight transpose: [z][K][N] fp32 -> bf16 [N][K] at dst + z*zStride ----
__global__ __launch_bounds__(256) void transpose_w_kernel(
    const float* __restrict__ src, unsigned short* __restrict__ dst,
    int K, int N, size_t zStride)
{
    __shared__ float tile[32][33];
    const float* s = src + (size_t)blockIdx.z * K * N;
    unsigned short* d = dst + (size_t)blockIdx.z * zStride;
    int k0 = blockIdx.y * 32, n0 = blockIdx.x * 32;
    int tx = threadIdx.x & 31, ty = threadIdx.x >> 5;   // 32 x 8
#pragma unroll
    for (int i = 0; i < 4; ++i)
        tile[ty + i * 8][tx] = s[(size_t)(k0 + ty + i * 8) * N + (n0 + tx)];
    __syncthreads();
#pragma unroll
    for (int i = 0; i < 4; ++i)
        d[(size_t)(n0 + ty + i * 8) * K + (k0 + tx)] = f2bf(tile[tx][ty + i * 8]);
}

// ---------------- x init: src_emb -> x (fp32, d_out) and xb (bf16) ----------------
__global__ __launch_bounds__(256) void convert_x_kernel(
    const float* __restrict__ src, float* __restrict__ x, unsigned short* __restrict__ xb, int n4)
{
    int i = blockIdx.x * blockDim.x + threadIdx.x;
    int stride = gridDim.x * blockDim.x;
    for (; i < n4; i += stride) {
        float4 f = ((const float4*)src)[i];
        ((float4*)x)[i] = f;
        ushort4 u;
        u.x = f2bf(f.x); u.y = f2bf(f.y); u.z = f2bf(f.z); u.w = f2bf(f.w);
        ((ushort4*)xb)[i] = u;
    }
}

// ---------------- bf16 GEMM: C[M][N] = A[M][K] @ Bt[N][K]^T ----------------
// LDS slot-XOR swizzle: LDS(row, slot) holds global(row, slot ^ ((row>>1)&3)),
// applied identically on the staging source address and the ds_read address
// (both-sides-or-neither, rule #21). Turns the 8-way b128 conflict into 2-way (free).
template<int BM, int BN, int WM, int WN, bool OUTBF, bool DORELU>
__global__ __launch_bounds__(WM * WN * 64) void gemm_kernel(
    const unsigned short* __restrict__ A,   // [M][K] bf16
    const unsigned short* __restrict__ Bt,  // [N][K] bf16
    float* __restrict__ Cf,                 // fp32 out (if !OUTBF)
    unsigned short* __restrict__ Cb,        // bf16 out (if OUTBF)
    const float* __restrict__ bias,         // [N] or null
    int M, int N, int K)
{
    constexpr int T = WM * WN * 64;
    constexpr int BK = 32;
    constexpr int TM = BM / WM, TN = BN / WN;
    __shared__ __align__(16) unsigned short As[BM * BK];
    __shared__ __align__(16) unsigned short Bs[BN * BK];
    int tid = threadIdx.x, lane = tid & 63, w = tid >> 6;
    int wr = w / WN, wc = w % WN;

    // XCD-bijective swizzle (all grids have nwg % 8 == 0)
    int gx = gridDim.x;
    int nwg = gx * gridDim.y;
    int flat = blockIdx.x + gx * blockIdx.y;
    int qq = nwg >> 3;
    int swz = (flat & 7) * qq + (flat >> 3);
    int bx = swz % gx, by = swz / gx;

    int mBase = by * BM, nBase = bx * BN;

    f32x4 acc[TM / 16][TN / 16];
#pragma unroll
    for (int i = 0; i < TM / 16; ++i)
#pragma unroll
        for (int j = 0; j < TN / 16; ++j) acc[i][j] = (f32x4){0.f, 0.f, 0.f, 0.f};

    for (int k0 = 0; k0 < K; k0 += BK) {
        // stage A: BM rows x 32 cols, 16B units; unit i -> (row=i>>2, slot=i&3)
#pragma unroll
        for (int it = 0; it < BM * 4 / T; ++it) {
            int i = it * T + tid;
            int row = i >> 2, slot = i & 3;
            int gcol = (slot ^ ((row >> 1) & 3)) * 8;
            const unsigned short* ga = A + (size_t)(mBase + row) * K + k0 + gcol;
            __builtin_amdgcn_global_load_lds(
                (const __attribute__((address_space(1))) void*)ga,
                (__attribute__((address_space(3))) void*)(As + i * 8), 16, 0, 0);
        }
#pragma unroll
        for (int it = 0; it < BN * 4 / T; ++it) {
            int i = it * T + tid;
            int row = i >> 2, slot = i & 3;
            int gcol = (slot ^ ((row >> 1) & 3)) * 8;
            const unsigned short* gb = Bt + (size_t)(nBase + row) * K + k0 + gcol;
            __builtin_amdgcn_global_load_lds(
                (const __attribute__((address_space(1))) void*)gb,
                (__attribute__((address_space(3))) void*)(Bs + i * 8), 16, 0, 0);
        }
        __syncthreads();

        int s = lane >> 4, rsel = lane & 15;
        bf16x8 a[TM / 16], b[TN / 16];
#pragma unroll
        for (int m = 0; m < TM / 16; ++m) {
            int row = wr * TM + m * 16 + rsel;
            a[m] = *(const bf16x8*)((const char*)As + row * 64 + ((s ^ ((row >> 1) & 3)) << 4));
        }
#pragma unroll
        for (int n = 0; n < TN / 16; ++n) {
            int row = wc * TN + n * 16 + rsel;
            b[n] = *(const bf16x8*)((const char*)Bs + row * 64 + ((s ^ ((row >> 1) & 3)) << 4));
        }
#pragma unroll
        for (int m = 0; m < TM / 16; ++m)
#pragma unroll
            for (int n = 0; n < TN / 16; ++n)
                acc[m][n] = __builtin_amdgcn_mfma_f32_16x16x32_bf16(a[m], b[n], acc[m][n], 0, 0, 0);
        __syncthreads();
    }

    // epilogue: C/D layout col=lane&15, row=(lane>>4)*4+j  [m89-verified]
    int rbase = (lane >> 4) * 4;
    int cloc = lane & 15;
#pragma unroll
    for (int m = 0; m < TM / 16; ++m) {
#pragma unroll
        for (int n = 0; n < TN / 16; ++n) {
            int col = nBase + wc * TN + n * 16 + cloc;
            float bv = bias ? bias[col] : 0.0f;
#pragma unroll
            for (int j = 0; j < 4; ++j) {
                int row = mBase + wr * TM + m * 16 + rbase + j;
                float val = acc[m][n][j] + bv;
                if (DORELU) val = fmaxf(val, 0.0f);
                if (OUTBF) Cb[(size_t)row * N + col] = f2bf(val);
                else       Cf[(size_t)row * N + col] = val;
            }
        }
    }
}

// ---------------- sparse relational attention (qkv packed bf16 [row][1536]) ----------
// one wave per (b,h,n); lane = d (DK=64)
__global__ __launch_bounds__(256) void attn_kernel(
    const unsigned short* __restrict__ qkv,
    const int* __restrict__ par, const int* __restrict__ bro,
    const float* __restrict__ relq, const float* __restrict__ relk,
    const float* __restrict__ relv, unsigned short* __restrict__ cb)
{
    int wid = blockIdx.x * 4 + (threadIdx.x >> 6);
    int lane = threadIdx.x & 63;
    int n = wid & (NN - 1);
    int t = wid >> 9;           // / NN
    int h = t & (HH - 1);
    int b = t >> 3;
    const int* edges = (h < PAR_HEADS) ? par : bro;

    float qd = bf2f(qkv[(size_t)(b * NN + n) * 1536 + h * DKK + lane]);
    float s[RR];
    int e[RR];
#pragma unroll
    for (int r = 0; r < RR; ++r) {
        e[r] = edges[(b * RR + r) * NN + n];
        float kd = bf2f(qkv[(size_t)(b * NN + e[r]) * 1536 + DMM + h * DKK + lane]);
        float rkd = relk[(h * RR + r) * DKK + lane];
        float rqd = relq[(h * RR + r) * DKK + lane];
        float tp = qd * kd + qd * rkd + rqd * kd;
#pragma unroll
        for (int off = 32; off > 0; off >>= 1) tp += __shfl_xor(tp, off, 64);
        s[r] = tp;
    }
    const float scale = 0.125f;  // 1/sqrt(64)
    float mx = -1e30f;
#pragma unroll
    for (int r = 0; r < RR; ++r) { s[r] *= scale; mx = fmaxf(mx, s[r]); }
    float denom = 0.f;
#pragma unroll
    for (int r = 0; r < RR; ++r) { s[r] = __expf(s[r] - mx); denom += s[r]; }
    float inv = 1.0f / denom;
    float od = 0.f;
#pragma unroll
    for (int r = 0; r < RR; ++r) {
        float vd = bf2f(qkv[(size_t)(b * NN + e[r]) * 1536 + 2 * DMM + h * DKK + lane]);
        float rvd = relv[(h * RR + r) * DKK + lane];
        od += s[r] * (vd + rvd);
    }
    od *= inv;
    cb[(size_t)(b * NN + n) * DMM + h * DKK + lane] = f2bf(od);
}

// ---------------- residual + LayerNorm ----------------
__global__ __launch_bounds__(256) void ln_kernel(
    const float* __restrict__ xin, const float* __restrict__ add,
    float* __restrict__ xout, unsigned short* __restrict__ xbout,
    const float* __restrict__ g, const float* __restrict__ bb)
{
    int row = blockIdx.x * 4 + (threadIdx.x >> 6);
    int lane = threadIdx.x & 63;
    const float* xr = xin + (size_t)row * DMM;
    const float* ar = add ? add + (size_t)row * DMM : nullptr;
    float vals[8];
    float s = 0.f;
#pragma unroll
    for (int j = 0; j < 8; ++j) {
        int c = lane + j * 64;
        float t = xr[c] + (ar ? ar[c] : 0.f);
        vals[j] = t;
        s += t;
    }
#pragma unroll
    for (int off = 32; off > 0; off >>= 1) s += __shfl_xor(s, off, 64);
    float mean = s * (1.0f / DMM);
    float s2 = 0.f;
#pragma unroll
    for (int j = 0; j < 8; ++j) { float d = vals[j] - mean; s2 += d * d; }
#pragma unroll
    for (int off = 32; off > 0; off >>= 1) s2 += __shfl_xor(s2, off, 64);
    float inv = rsqrtf(s2 * (1.0f / DMM) + EPSV);
#pragma unroll
    for (int j = 0; j < 8; ++j) {
        int c = lane + j * 64;
        float y = (vals[j] - mean) * inv * g[c] + bb[c];
        xout[(size_t)row * DMM + c] = y;
        if (xbout) xbout[(size_t)row * DMM + c] = f2bf(y);
    }
}

extern "C" void kernel_launch(void* const* d_in, const int* in_sizes, int n_in,
                              void* d_out, int out_size, void* d_ws, size_t ws_size,
                              hipStream_t stream)
{
    const float* src_emb = (const float*)d_in[0];
    const int*   par     = (const int*)d_in[1];
    const int*   bro     = (const int*)d_in[2];
    const float* rel_q   = (const float*)d_in[3];
    const float* rel_k   = (const float*)d_in[4];
    const float* rel_v   = (const float*)d_in[5];
    const float* Wq      = (const float*)d_in[6];
    const float* Wk      = (const float*)d_in[7];
    const float* Wv      = (const float*)d_in[8];
    const float* Wo      = (const float*)d_in[9];
    const float* ln1_g   = (const float*)d_in[10];
    const float* ln1_b   = (const float*)d_in[11];
    const float* W1      = (const float*)d_in[12];
    const float* b1      = (const float*)d_in[13];
    const float* W2      = (const float*)d_in[14];
    const float* b2      = (const float*)d_in[15];
    const float* ln2_g   = (const float*)d_in[16];
    const float* ln2_b   = (const float*)d_in[17];
    const float* normf_g = (const float*)d_in[18];
    const float* normf_b = (const float*)d_in[19];

    const size_t MB = 1024 * 1024;
    const int M = BB * NN;  // 8192
    char* ws = (char*)d_ws;
    unsigned short* qkvb = (unsigned short*)(ws + 0 * MB);    // 24 MB
    float*          t1   = (float*)(ws + 24 * MB);            // 16 MB
    unsigned short* h1   = (unsigned short*)(ws + 40 * MB);   // 32 MB
    unsigned short* xb   = (unsigned short*)(ws + 72 * MB);   // 8 MB
    unsigned short* cbuf = (unsigned short*)(ws + 80 * MB);   // 8 MB
    unsigned short* wqkvT = (unsigned short*)(ws + 88 * MB);  // L*1536*512*2 = 3 MB
    unsigned short* woT  = wqkvT + (size_t)LL * 1536 * DMM;
    unsigned short* w1T  = woT + (size_t)LL * DMM * DMM;
    unsigned short* w2T  = w1T + (size_t)LL * DMM * DFFV;
    float* x = (float*)d_out;

    const size_t qkvStride = (size_t)1536 * DMM;  // per-layer packed qkv weight
    transpose_w_kernel<<<dim3(DMM / 32, DMM / 32, LL), 256, 0, stream>>>(
        Wq, wqkvT + 0 * DMM * DMM, DMM, DMM, qkvStride);
    transpose_w_kernel<<<dim3(DMM / 32, DMM / 32, LL), 256, 0, stream>>>(
        Wk, wqkvT + 1 * DMM * DMM, DMM, DMM, qkvStride);
    transpose_w_kernel<<<dim3(DMM / 32, DMM / 32, LL), 256, 0, stream>>>(
        Wv, wqkvT + 2 * DMM * DMM, DMM, DMM, qkvStride);
    transpose_w_kernel<<<dim3(DMM / 32, DMM / 32, LL), 256, 0, stream>>>(
        Wo, woT, DMM, DMM, (size_t)DMM * DMM);
    transpose_w_kernel<<<dim3(DFFV / 32, DMM / 32, LL), 256, 0, stream>>>(
        W1, w1T, DMM, DFFV, (size_t)DMM * DFFV);
    transpose_w_kernel<<<dim3(DMM / 32, DFFV / 32, LL), 256, 0, stream>>>(
        W2, w2T, DFFV, DMM, (size_t)DMM * DFFV);

    convert_x_kernel<<<2048, 256, 0, stream>>>(src_emb, x, xb, M * DMM / 4);

    for (int l = 0; l < LL; ++l) {
        const unsigned short* wqkv_l = wqkvT + (size_t)l * 1536 * DMM;
        const unsigned short* wo_l = woT + (size_t)l * DMM * DMM;
        const unsigned short* w1_l = w1T + (size_t)l * DMM * DFFV;
        const unsigned short* w2_l = w2T + (size_t)l * DFFV * DMM;

        // fused QKV: [8192,512] @ [512,1536] -> bf16 qkvb ; grid 768 = 3 blocks/CU
        gemm_kernel<128, 128, 2, 2, true, false><<<dim3(1536 / 128, M / 128), 256, 0, stream>>>(
            xb, wqkv_l, nullptr, qkvb, nullptr, M, 1536, DMM);

        attn_kernel<<<BB * HH * NN / 4, 256, 0, stream>>>(qkvb, par, bro,
                                                          rel_q, rel_k, rel_v, cbuf);

        // Wo: N=512, BN=64 -> grid 512 = 2 blocks/CU
        gemm_kernel<128, 64, 2, 2, false, false><<<dim3(512 / 64, M / 128), 256, 0, stream>>>(
            cbuf, wo_l, t1, nullptr, nullptr, M, DMM, DMM);
        ln_kernel<<<M / 4, 256, 0, stream>>>(x, t1, x, xb, ln1_g + l * DMM, ln1_b + l * DMM);

        // W1: N=2048 -> grid 1024 = 4 blocks/CU, bias+relu, bf16 out
        gemm_kernel<128, 128, 2, 2, true, true><<<dim3(DFFV / 128, M / 128), 256, 0, stream>>>(
            xb, w1_l, nullptr, h1, b1 + l * DFFV, M, DFFV, DMM);
        // W2: N=512, K=2048, BN=64 -> grid 512
        gemm_kernel<128, 64, 2, 2, false, false><<<dim3(512 / 64, M / 128), 256, 0, stream>>>(
            h1, w2_l, t1, nullptr, b2 + l * DMM, M, DMM, DFFV);
        ln_kernel<<<M / 4, 256, 0, stream>>>(x, t1, x, xb, ln2_g + l * DMM, ln2_b + l * DMM);
    }

    ln_kernel<<<M / 4, 256, 0, stream>>>(x, nullptr, x, nullptr, normf_g, normf_b);
}

// Round 3
// 436.709 us; speedup vs baseline: 1.3331x; 1.0568x over previous
//
#include <hip/hip_runtime.h>
#include <hip/hip_bf16.h>

// FastASTEncoder round 3: uniform 128x64/BK=64 GEMM (8-slot XOR swizzle),
// split-K=2 for Wo/W2 with partial-sum folded into LN, QKV grid 1536, W1 grid 2048.
//
// Workspace (~92 MiB):
//   [0,32M)   p0/p1 fp32 partials [2][8192][512]  (overlaps qkvb bf16 [8192][1536] = 24MB)
//   [32,64M)  h1   bf16 [8192][2048]
//   [64,72M)  xb   bf16 [8192][512]
//   [72,80M)  cbuf bf16 [8192][512]
//   [80M+)    transposed bf16 weights (qkv packed 3MB, wo 1MB, w1 4MB, w2 4MB)

#define BB 16
#define NN 512
#define DMM 512
#define HH 8
#define DKK 64
#define RR 8
#define LL 2
#define DFFV 2048
#define PAR_HEADS 4
#define EPSV 1e-5f

typedef __bf16 bf16x8 __attribute__((ext_vector_type(8)));
typedef float f32x4 __attribute__((ext_vector_type(4)));

__device__ __forceinline__ unsigned short f2bf(float f) {
    unsigned u = __float_as_uint(f);
    u += 0x7fff + ((u >> 16) & 1);   // RNE
    return (unsigned short)(u >> 16);
}
__device__ __forceinline__ float bf2f(unsigned short u) {
    return __uint_as_float(((unsigned)u) << 16);
}

// ---------------- fused transpose for the four [512][512] weight sets ----------------
// z: layer = z>>2, which = z&3 (0=Wq,1=Wk,2=Wv packed into wqkvT; 3=Wo)
__global__ __launch_bounds__(256) void transpose_qkvo_kernel(
    const float* __restrict__ Wq, const float* __restrict__ Wk,
    const float* __restrict__ Wv, const float* __restrict__ Wo,
    unsigned short* __restrict__ wqkvT, unsigned short* __restrict__ woT)
{
    __shared__ float tile[32][33];
    int layer = blockIdx.z >> 2, which = blockIdx.z & 3;
    const float* s = (which == 0 ? Wq : which == 1 ? Wk : which == 2 ? Wv : Wo)
                     + (size_t)layer * DMM * DMM;
    unsigned short* d = (which < 3)
        ? wqkvT + (size_t)layer * 1536 * DMM + (size_t)which * DMM * DMM
        : woT + (size_t)layer * DMM * DMM;
    int k0 = blockIdx.y * 32, n0 = blockIdx.x * 32;
    int tx = threadIdx.x & 31, ty = threadIdx.x >> 5;
#pragma unroll
    for (int i = 0; i < 4; ++i)
        tile[ty + i * 8][tx] = s[(size_t)(k0 + ty + i * 8) * DMM + (n0 + tx)];
    __syncthreads();
#pragma unroll
    for (int i = 0; i < 4; ++i)
        d[(size_t)(n0 + ty + i * 8) * DMM + (k0 + tx)] = f2bf(tile[tx][ty + i * 8]);
}

// generic transpose [z][K][N] fp32 -> bf16 [N][K] (for W1, W2)
__global__ __launch_bounds__(256) void transpose_w_kernel(
    const float* __restrict__ src, unsigned short* __restrict__ dst,
    int K, int N, size_t zStride)
{
    __shared__ float tile[32][33];
    const float* s = src + (size_t)blockIdx.z * K * N;
    unsigned short* d = dst + (size_t)blockIdx.z * zStride;
    int k0 = blockIdx.y * 32, n0 = blockIdx.x * 32;
    int tx = threadIdx.x & 31, ty = threadIdx.x >> 5;
#pragma unroll
    for (int i = 0; i < 4; ++i)
        tile[ty + i * 8][tx] = s[(size_t)(k0 + ty + i * 8) * N + (n0 + tx)];
    __syncthreads();
#pragma unroll
    for (int i = 0; i < 4; ++i)
        d[(size_t)(n0 + ty + i * 8) * K + (k0 + tx)] = f2bf(tile[tx][ty + i * 8]);
}

// ---------------- x init ----------------
__global__ __launch_bounds__(256) void convert_x_kernel(
    const float* __restrict__ src, float* __restrict__ x, unsigned short* __restrict__ xb, int n4)
{
    int i = blockIdx.x * blockDim.x + threadIdx.x;
    int stride = gridDim.x * blockDim.x;
    for (; i < n4; i += stride) {
        float4 f = ((const float4*)src)[i];
        ((float4*)x)[i] = f;
        ushort4 u;
        u.x = f2bf(f.x); u.y = f2bf(f.y); u.z = f2bf(f.z); u.w = f2bf(f.w);
        ((ushort4*)xb)[i] = u;
    }
}

// ---------------- bf16 GEMM: C[M][N] = A[M][K] @ Bt[N][K]^T ----------------
// Tile 128x64, BK=64, 4 waves (2x2), wave tile 64x32, 16 MFMA/wave/K-step.
// LDS row = 128B = 8 x 16B slots; LDS(row,slot) = global(row, slot^(row&7))
// (both-sides XOR swizzle, rule #21). Split-K via blockIdx.z: each split z
// handles k in [z*kLen, (z+1)*kLen), writing to Cf/Cb + z*M*N.
template<bool OUTBF, bool DORELU>
__global__ __launch_bounds__(256) void gemm_kernel(
    const unsigned short* __restrict__ A,   // [M][K] bf16
    const unsigned short* __restrict__ Bt,  // [N][K] bf16
    float* __restrict__ Cf,                 // fp32 out (if !OUTBF)
    unsigned short* __restrict__ Cb,        // bf16 out (if OUTBF)
    const float* __restrict__ bias,         // [N] or null
    int M, int N, int K, int kLen)
{
    constexpr int BM = 128, BN = 64, BK = 64;
    __shared__ __align__(16) unsigned short As[BM * BK];
    __shared__ __align__(16) unsigned short Bs[BN * BK];
    int tid = threadIdx.x, lane = tid & 63, w = tid >> 6;
    int wr = w >> 1, wc = w & 1;

    // XCD-bijective swizzle over (x,y); all grids have nwg % 8 == 0
    int gx = gridDim.x;
    int nwg = gx * gridDim.y;
    int flat = blockIdx.x + gx * blockIdx.y;
    int qq = nwg >> 3;
    int swz = (flat & 7) * qq + (flat >> 3);
    int bx = swz % gx, by = swz / gx;
    int mBase = by * BM, nBase = bx * BN;
    int kStart = blockIdx.z * kLen;

    f32x4 acc[4][2];
#pragma unroll
    for (int i = 0; i < 4; ++i)
#pragma unroll
        for (int j = 0; j < 2; ++j) acc[i][j] = (f32x4){0.f, 0.f, 0.f, 0.f};

    for (int k0 = kStart; k0 < kStart + kLen; k0 += BK) {
        // stage A: 1024 16B units (row=i>>3, slot=i&7), source column pre-XOR-swizzled
#pragma unroll
        for (int it = 0; it < 4; ++it) {
            int i = it * 256 + tid;
            int row = i >> 3, slot = i & 7;
            int gcol = (slot ^ (row & 7)) * 8;
            const unsigned short* ga = A + (size_t)(mBase + row) * K + k0 + gcol;
            __builtin_amdgcn_global_load_lds(
                (const __attribute__((address_space(1))) void*)ga,
                (__attribute__((address_space(3))) void*)(As + i * 8), 16, 0, 0);
        }
#pragma unroll
        for (int it = 0; it < 2; ++it) {
            int i = it * 256 + tid;
            int row = i >> 3, slot = i & 7;
            int gcol = (slot ^ (row & 7)) * 8;
            const unsigned short* gb = Bt + (size_t)(nBase + row) * K + k0 + gcol;
            __builtin_amdgcn_global_load_lds(
                (const __attribute__((address_space(1))) void*)gb,
                (__attribute__((address_space(3))) void*)(Bs + i * 8), 16, 0, 0);
        }
        __syncthreads();

        int rsel = lane & 15, g0 = lane >> 4;
        bf16x8 a[4][2], b[2][2];
#pragma unroll
        for (int m = 0; m < 4; ++m) {
            int row = wr * 64 + m * 16 + rsel;
#pragma unroll
            for (int ks = 0; ks < 2; ++ks) {
                int s = (g0 + ks * 4) ^ (row & 7);
                a[m][ks] = *(const bf16x8*)((const char*)As + row * 128 + s * 16);
            }
        }
#pragma unroll
        for (int n = 0; n < 2; ++n) {
            int row = wc * 32 + n * 16 + rsel;
#pragma unroll
            for (int ks = 0; ks < 2; ++ks) {
                int s = (g0 + ks * 4) ^ (row & 7);
                b[n][ks] = *(const bf16x8*)((const char*)Bs + row * 128 + s * 16);
            }
        }
#pragma unroll
        for (int m = 0; m < 4; ++m)
#pragma unroll
            for (int n = 0; n < 2; ++n)
#pragma unroll
                for (int ks = 0; ks < 2; ++ks)
                    acc[m][n] = __builtin_amdgcn_mfma_f32_16x16x32_bf16(a[m][ks], b[n][ks], acc[m][n], 0, 0, 0);
        __syncthreads();
    }

    // epilogue: C/D layout col=lane&15, row=(lane>>4)*4+j  [m89-verified]
    size_t zoff = (size_t)blockIdx.z * M * N;
    int rbase = (lane >> 4) * 4;
    int cloc = lane & 15;
#pragma unroll
    for (int m = 0; m < 4; ++m) {
#pragma unroll
        for (int n = 0; n < 2; ++n) {
            int col = nBase + wc * 32 + n * 16 + cloc;
            float bv = bias ? bias[col] : 0.0f;
#pragma unroll
            for (int j = 0; j < 4; ++j) {
                int row = mBase + wr * 64 + m * 16 + rbase + j;
                float val = acc[m][n][j] + bv;
                if (DORELU) val = fmaxf(val, 0.0f);
                if (OUTBF) Cb[zoff + (size_t)row * N + col] = f2bf(val);
                else       Cf[zoff + (size_t)row * N + col] = val;
            }
        }
    }
}

// ---------------- sparse relational attention (qkv packed bf16 [row][1536]) ----------
__global__ __launch_bounds__(256) void attn_kernel(
    const unsigned short* __restrict__ qkv,
    const int* __restrict__ par, const int* __restrict__ bro,
    const float* __restrict__ relq, const float* __restrict__ relk,
    const float* __restrict__ relv, unsigned short* __restrict__ cb)
{
    int wid = blockIdx.x * 4 + (threadIdx.x >> 6);
    int lane = threadIdx.x & 63;
    int n = wid & (NN - 1);
    int t = wid >> 9;
    int h = t & (HH - 1);
    int b = t >> 3;
    const int* edges = (h < PAR_HEADS) ? par : bro;

    float qd = bf2f(qkv[(size_t)(b * NN + n) * 1536 + h * DKK + lane]);
    float s[RR];
    int e[RR];
#pragma unroll
    for (int r = 0; r < RR; ++r) {
        e[r] = edges[(b * RR + r) * NN + n];
        float kd = bf2f(qkv[(size_t)(b * NN + e[r]) * 1536 + DMM + h * DKK + lane]);
        float rkd = relk[(h * RR + r) * DKK + lane];
        float rqd = relq[(h * RR + r) * DKK + lane];
        float tp = qd * kd + qd * rkd + rqd * kd;
#pragma unroll
        for (int off = 32; off > 0; off >>= 1) tp += __shfl_xor(tp, off, 64);
        s[r] = tp;
    }
    const float scale = 0.125f;
    float mx = -1e30f;
#pragma unroll
    for (int r = 0; r < RR; ++r) { s[r] *= scale; mx = fmaxf(mx, s[r]); }
    float denom = 0.f;
#pragma unroll
    for (int r = 0; r < RR; ++r) { s[r] = __expf(s[r] - mx); denom += s[r]; }
    float inv = 1.0f / denom;
    float od = 0.f;
#pragma unroll
    for (int r = 0; r < RR; ++r) {
        float vd = bf2f(qkv[(size_t)(b * NN + e[r]) * 1536 + 2 * DMM + h * DKK + lane]);
        float rvd = relv[(h * RR + r) * DKK + lane];
        od += s[r] * (vd + rvd);
    }
    od *= inv;
    cb[(size_t)(b * NN + n) * DMM + h * DKK + lane] = f2bf(od);
}

// ---------------- residual(+partials+bias) + LayerNorm ----------------
__global__ __launch_bounds__(256) void ln_kernel(
    const float* __restrict__ xin, const float* __restrict__ add0,
    const float* __restrict__ add1, const float* __restrict__ bias,
    float* __restrict__ xout, unsigned short* __restrict__ xbout,
    const float* __restrict__ g, const float* __restrict__ bb)
{
    int row = blockIdx.x * 4 + (threadIdx.x >> 6);
    int lane = threadIdx.x & 63;
    const float* xr = xin + (size_t)row * DMM;
    const float* a0 = add0 ? add0 + (size_t)row * DMM : nullptr;
    const float* a1 = add1 ? add1 + (size_t)row * DMM : nullptr;
    float vals[8];
    float s = 0.f;
#pragma unroll
    for (int j = 0; j < 8; ++j) {
        int c = lane + j * 64;
        float t = xr[c];
        if (a0) t += a0[c];
        if (a1) t += a1[c];
        if (bias) t += bias[c];
        vals[j] = t;
        s += t;
    }
#pragma unroll
    for (int off = 32; off > 0; off >>= 1) s += __shfl_xor(s, off, 64);
    float mean = s * (1.0f / DMM);
    float s2 = 0.f;
#pragma unroll
    for (int j = 0; j < 8; ++j) { float d = vals[j] - mean; s2 += d * d; }
#pragma unroll
    for (int off = 32; off > 0; off >>= 1) s2 += __shfl_xor(s2, off, 64);
    float inv = rsqrtf(s2 * (1.0f / DMM) + EPSV);
#pragma unroll
    for (int j = 0; j < 8; ++j) {
        int c = lane + j * 64;
        float y = (vals[j] - mean) * inv * g[c] + bb[c];
        xout[(size_t)row * DMM + c] = y;
        if (xbout) xbout[(size_t)row * DMM + c] = f2bf(y);
    }
}

extern "C" void kernel_launch(void* const* d_in, const int* in_sizes, int n_in,
                              void* d_out, int out_size, void* d_ws, size_t ws_size,
                              hipStream_t stream)
{
    const float* src_emb = (const float*)d_in[0];
    const int*   par     = (const int*)d_in[1];
    const int*   bro     = (const int*)d_in[2];
    const float* rel_q   = (const float*)d_in[3];
    const float* rel_k   = (const float*)d_in[4];
    const float* rel_v   = (const float*)d_in[5];
    const float* Wq      = (const float*)d_in[6];
    const float* Wk      = (const float*)d_in[7];
    const float* Wv      = (const float*)d_in[8];
    const float* Wo      = (const float*)d_in[9];
    const float* ln1_g   = (const float*)d_in[10];
    const float* ln1_b   = (const float*)d_in[11];
    const float* W1      = (const float*)d_in[12];
    const float* b1      = (const float*)d_in[13];
    const float* W2      = (const float*)d_in[14];
    const float* b2      = (const float*)d_in[15];
    const float* ln2_g   = (const float*)d_in[16];
    const float* ln2_b   = (const float*)d_in[17];
    const float* normf_g = (const float*)d_in[18];
    const float* normf_b = (const float*)d_in[19];

    const size_t MB = 1024 * 1024;
    const int M = BB * NN;  // 8192
    char* ws = (char*)d_ws;
    float*          p    = (float*)(ws + 0 * MB);             // [2][8192][512] fp32, 32MB
    unsigned short* qkvb = (unsigned short*)(ws + 0 * MB);    // overlaps p (disjoint lifetime)
    unsigned short* h1   = (unsigned short*)(ws + 32 * MB);   // 32MB
    unsigned short* xb   = (unsigned short*)(ws + 64 * MB);   // 8MB
    unsigned short* cbuf = (unsigned short*)(ws + 72 * MB);   // 8MB
    unsigned short* wqkvT = (unsigned short*)(ws + 80 * MB);
    unsigned short* woT  = wqkvT + (size_t)LL * 1536 * DMM;
    unsigned short* w1T  = woT + (size_t)LL * DMM * DMM;
    unsigned short* w2T  = w1T + (size_t)LL * DMM * DFFV;
    float* p0 = p;
    float* p1 = p + (size_t)M * DMM;
    float* x = (float*)d_out;

    transpose_qkvo_kernel<<<dim3(16, 16, LL * 4), 256, 0, stream>>>(
        Wq, Wk, Wv, Wo, wqkvT, woT);
    transpose_w_kernel<<<dim3(DFFV / 32, DMM / 32, LL), 256, 0, stream>>>(
        W1, w1T, DMM, DFFV, (size_t)DMM * DFFV);
    transpose_w_kernel<<<dim3(DMM / 32, DFFV / 32, LL), 256, 0, stream>>>(
        W2, w2T, DFFV, DMM, (size_t)DMM * DFFV);

    convert_x_kernel<<<2048, 256, 0, stream>>>(src_emb, x, xb, M * DMM / 4);

    for (int l = 0; l < LL; ++l) {
        const unsigned short* wqkv_l = wqkvT + (size_t)l * 1536 * DMM;
        const unsigned short* wo_l = woT + (size_t)l * DMM * DMM;
        const unsigned short* w1_l = w1T + (size_t)l * DMM * DFFV;
        const unsigned short* w2_l = w2T + (size_t)l * DFFV * DMM;

        // fused QKV: [8192,512]@[512,1536] -> bf16 qkvb; grid 1536 = 6 blocks/CU
        gemm_kernel<true, false><<<dim3(1536 / 64, M / 128, 1), 256, 0, stream>>>(
            xb, wqkv_l, nullptr, qkvb, nullptr, M, 1536, DMM, DMM);

        attn_kernel<<<BB * HH * NN / 4, 256, 0, stream>>>(qkvb, par, bro,
                                                          rel_q, rel_k, rel_v, cbuf);

        // Wo: split-K=2, grid (8,64,2) = 1024 blocks; partials p0,p1 summed in ln1
        gemm_kernel<false, false><<<dim3(512 / 64, M / 128, 2), 256, 0, stream>>>(
            cbuf, wo_l, p, nullptr, nullptr, M, DMM, DMM, DMM / 2);
        ln_kernel<<<M / 4, 256, 0, stream>>>(x, p0, p1, nullptr, x, xb,
                                             ln1_g + l * DMM, ln1_b + l * DMM);

        // W1: bias+relu, bf16 out; grid 2048 = 8 blocks/CU
        gemm_kernel<true, true><<<dim3(DFFV / 64, M / 128, 1), 256, 0, stream>>>(
            xb, w1_l, nullptr, h1, b1 + l * DFFV, M, DFFV, DMM, DMM);
        // W2: split-K=2 (K=1024 each), grid 1024; b2 added in ln2
        gemm_kernel<false, false><<<dim3(512 / 64, M / 128, 2), 256, 0, stream>>>(
            h1, w2_l, p, nullptr, nullptr, M, DMM, DFFV, DFFV / 2);
        ln_kernel<<<M / 4, 256, 0, stream>>>(x, p0, p1, b2 + l * DMM, x, xb,
                                             ln2_g + l * DMM, ln2_b + l * DMM);
    }

    ln_kernel<<<M / 4, 256, 0, stream>>>(x, nullptr, nullptr, nullptr, x, nullptr,
                                         normf_g, normf_b);
}